// Round 2
// 750.442 us; speedup vs baseline: 1.4530x; 1.4530x over previous
//
#include <hip/hip_runtime.h>

// ---------------------------------------------------------------------------
// Seq2Seq LSTM (enc 64 steps -> dec 63 steps -> FC to vocab), MI355X gfx950.
// Round 2: split the sequential recurrence across 8 CUs per batch element.
//   k_pack_whh : Whh -> f16, packed-transposed [k8][row] (coalesced loads)
//   k_pack_wih : Wih -> f32, packed-transposed [e4][g]
//   k_pre      : embeddings + x@Wih^T + b for all 127 steps (parallel)
//   k_init     : zero the h-exchange word buffer (stale tags across replays!)
//   k_lstm2    : 256 WGs = 8 slices x 32 batch. Each WG owns 128 gate rows
//                (4 gates x 32 cols); enc+dec weight slices live in LDS for
//                the whole kernel (129 KB -> exactly 1 WG/CU, all resident).
//                Per step, h (256 f16) is exchanged between the 8 WGs of a
//                batch element via tagged u64 words (hi32=step tag, lo32=
//                2xf16), relaxed agent-scope atomics, parity double-buffer.
//                Chain safety: WG (b,j) can only publish h_{s+2} (overwriting
//                slot of h_s) after polling all peers' h_{s+1}, which implies
//                every peer finished step s and hence consumed h_s. Exact-tag
//                spin therefore cannot deadlock; zero-init prevents stale-tag
//                aliasing across graph replays.
//   k_zero0    : out[:,0,:] = 0
//   k_fc       : bf16 MFMA GEMM [2016x256]@[256x32000] + bias -> out[:,1:,:]
// Scratch: pre-activations + packed weights + h-words carved from d_out (all
// dead before any output writes); d_ws holds decoder hidden states (8.3 MB).
// ---------------------------------------------------------------------------

typedef _Float16 f16x2 __attribute__((ext_vector_type(2)));
typedef short short8 __attribute__((ext_vector_type(8)));
typedef float f32x4 __attribute__((ext_vector_type(4)));
typedef unsigned long long u64;

#define DEV __device__ __forceinline__

static constexpr int Vv = 32000, Ee = 128, Hh = 256, Bb = 32, Ss = 64, Tt = 64;
static constexpr int G4 = 4 * Hh;             // 1024 gate outputs
static constexpr int MR = (Tt - 1) * Bb;      // 2016 logit rows
static constexpr size_t OUT_BT = (size_t)Tt * Vv;  // per-batch out stride (2,048,000)

// scratch carved from d_out (bytes)
static constexpr size_t OFF_ENCPRE = 0;                                    // 64*32*1024 f32
static constexpr size_t OFF_DECPRE = OFF_ENCPRE + (size_t)Ss * Bb * G4 * 4;  // 8,388,608
static constexpr size_t OFF_WQE    = OFF_DECPRE + (size_t)(Tt - 1) * Bb * G4 * 4; // +8,257,536
static constexpr size_t OFF_WQD    = OFF_WQE + (size_t)G4 * Hh * 2;        // +524,288
static constexpr size_t OFF_WPE    = OFF_WQD + (size_t)G4 * Hh * 2;
static constexpr size_t OFF_WPD    = OFF_WPE + (size_t)G4 * Ee * 4;
static constexpr size_t OFF_HW     = OFF_WPD + (size_t)G4 * Ee * 4;        // h-words: 2*32*128 u64 = 64 KB
// end = OFF_HW + 65,536 = 18,808,832 bytes << 262,144,000-byte output buffer

DEV float sigm(float x) { return 1.0f / (1.0f + expf(-x)); }

DEV unsigned short f2bf(float x) {
  unsigned u = __float_as_uint(x);
  u = u + 0x7fffu + ((u >> 16) & 1u);   // RNE
  return (unsigned short)(u >> 16);
}

DEV float dot2(unsigned wu, unsigned hu, float acc) {
  union { unsigned u; f16x2 v; } a, b;
  a.u = wu; b.u = hu;
#if __has_builtin(__builtin_amdgcn_fdot2)
  return __builtin_amdgcn_fdot2(a.v, b.v, acc, false);
#else
  return acc + (float)a.v.x * (float)b.v.x + (float)a.v.y * (float)b.v.y;
#endif
}

// --- pack Whh [1024][256] f32 -> f16 layout: dst[((k>>3)*1024 + r)*8 + (k&7)]
__global__ __launch_bounds__(256) void k_pack_whh(const float* __restrict__ src,
                                                  _Float16* __restrict__ dst) {
  int tid = blockIdx.x * 256 + threadIdx.x;
  if (tid >= G4 * Hh) return;
  int r = tid >> 8, k = tid & 255;
  dst[((size_t)(k >> 3) * G4 + r) * 8 + (k & 7)] = (_Float16)src[tid];
}

// --- pack Wih [1024][128] f32 -> f32 layout: dst[((e>>2)*1024 + g)*4 + (e&3)]
__global__ __launch_bounds__(256) void k_pack_wih(const float* __restrict__ src,
                                                  float* __restrict__ dst) {
  int tid = blockIdx.x * 256 + threadIdx.x;
  if (tid >= G4 * Ee) return;
  int g = tid >> 7, e = tid & 127;
  dst[((size_t)(e >> 2) * G4 + g) * 4 + (e & 3)] = src[tid];
}

// --- zero the h-exchange buffer (must run every launch: tags repeat across
// graph replays and a stale tag==step word would be consumed as fresh data)
__global__ __launch_bounds__(256) void k_init(u64* __restrict__ w) {
  w[blockIdx.x * 256 + threadIdx.x] = 0ull;   // grid 32 -> 8192 words
}

// --- pre[step][b][g] = emb[tok][.] @ Wih^T + b   (127 steps x 32 batch x 1024)
// grid: 127*4 blocks (4 batch-groups of 8), 1024 threads (one per gate col)
__global__ __launch_bounds__(1024) void k_pre(
    const int* __restrict__ src, const int* __restrict__ trg,
    const float* __restrict__ enc_emb, const float* __restrict__ dec_emb,
    const float* __restrict__ WpE, const float* __restrict__ WpD,
    const float* __restrict__ enc_b, const float* __restrict__ dec_b,
    float* __restrict__ enc_pre, float* __restrict__ dec_pre) {
  int blk = blockIdx.x;           // 0..507
  int step = blk >> 2;            // 0..126
  int b0 = (blk & 3) * 8;
  bool enc = step < Ss;
  int ts = enc ? step : step - Ss;            // enc s or dec t
  const int*   tok  = enc ? src : trg;
  const float* emb  = enc ? enc_emb : dec_emb;
  const float* Wp   = enc ? WpE : WpD;
  const float* bias = enc ? enc_b : dec_b;
  float* pre = enc ? (enc_pre + ((size_t)step * Bb + b0) * G4)
                   : (dec_pre + ((size_t)(step - Ss) * Bb + b0) * G4);

  __shared__ __align__(16) float xs[8][128];
  int tid = threadIdx.x;
  {
    int bl = tid >> 7, e = tid & 127;
    int token = tok[(b0 + bl) * 64 + ts];
    xs[bl][e] = emb[(size_t)token * Ee + e];
  }
  __syncthreads();

  int g = tid;
  float acc[8];
  float bv = bias[g];
#pragma unroll
  for (int bb = 0; bb < 8; ++bb) acc[bb] = bv;

  const f32x4* w4 = (const f32x4*)Wp;
  const f32x4(*x4)[32] = (const f32x4(*)[32])xs;
#pragma unroll 4
  for (int e4 = 0; e4 < 32; ++e4) {
    f32x4 w = w4[(size_t)e4 * G4 + g];
#pragma unroll
    for (int bb = 0; bb < 8; ++bb) {
      f32x4 xv = x4[bb][e4];
      acc[bb] += w.x * xv.x + w.y * xv.y + w.z * xv.z + w.w * xv.w;
    }
  }
#pragma unroll
  for (int bb = 0; bb < 8; ++bb) pre[(size_t)bb * G4 + g] = acc[bb];
}

// --- distributed sequential recurrence: 8 WGs per batch element.
// blockIdx = j*32 + b  (slice j 0..7, batch b 0..31; b%8 keeps a batch's WGs
// on one XCD under round-robin dispatch — locality heuristic only).
// Thread map (256 threads): wave wv = gate (i,f,g,o), lane&31 = local column,
// lane>>5 = K-half. Weight row = wv*256 + j*32 + (lane&31); each (row,khalf)
// thread does a 128-element half-dot from LDS-resident weights.
__global__ __launch_bounds__(256, 1) void k_lstm2(
    const float* __restrict__ enc_pre, const float* __restrict__ dec_pre,
    const _Float16* __restrict__ WqE, const _Float16* __restrict__ WqD,
    u64* __restrict__ hword, float* __restrict__ hs) {
  const int bid = blockIdx.x;
  const int j = bid >> 5, b = bid & 31;
  const int t = threadIdx.x;
  const int wv = t >> 6, l = t & 63;
  const int c_loc = l & 31, khalf = l >> 5;
  const int r_loc = wv * 32 + c_loc;           // 0..127 slice-local row
  const int row = wv * 256 + j * 32 + c_loc;   // global gate row

  __shared__ uint4 wlds[2][32][128];           // 128 KB: [enc/dec][K8][r_loc]
  __shared__ unsigned hbits[128];              // h: 128 x (2 f16)
  __shared__ float gbuf[4][32];
  __shared__ float hstash[32];

  // one-time stage: both weight slices -> LDS (64 KB each, read from L2 once)
  {
    const uint4* gE = (const uint4*)WqE + row;
    const uint4* gD = (const uint4*)WqD + row;
#pragma unroll 4
    for (int kk = 0; kk < 32; ++kk) wlds[0][kk][r_loc] = gE[(size_t)kk * G4];
#pragma unroll 4
    for (int kk = 0; kk < 32; ++kk) wlds[1][kk][r_loc] = gD[(size_t)kk * G4];
  }
  float c = 0.0f;                              // t<32: cell state, col j*32+t
  __syncthreads();

  for (int step = 0; step < 127; ++step) {
    const bool enc = step < Ss;
    const float* pre = (enc ? enc_pre + (size_t)step * (Bb * G4)
                            : dec_pre + (size_t)(step - Ss) * (Bb * G4)) +
                       (size_t)b * G4;
    float pv = pre[row];                       // issued early, used post-dots

    // --- acquire h_step (tag==step) into LDS; data rides in the tagged word
    if (t < 128) {
      if (step == 0) {
        hbits[t] = 0u;
      } else {
        u64* wp = hword + ((size_t)(step & 1) * 32 + b) * 128 + t;
        u64 v;
        do {
          v = __hip_atomic_load(wp, __ATOMIC_RELAXED, __HIP_MEMORY_SCOPE_AGENT);
        } while ((unsigned)(v >> 32) != (unsigned)step);
        hbits[t] = (unsigned)v;
      }
    }
    __syncthreads();                           // B1: h ready (also: gbuf free)

    // --- 128-element half-dot per thread, weights from LDS
    const uint4* wl = &wlds[enc ? 0 : 1][khalf * 16][0];
    const uint4* hv4 = (const uint4*)hbits;    // 32 x uint4 (8 f16 each)
    float a0 = 0.f, a1 = 0.f, a2 = 0.f, a3 = 0.f;
#pragma unroll
    for (int k8 = 0; k8 < 16; ++k8) {
      uint4 w8 = wl[k8 * 128 + r_loc];         // lanes contiguous: conflict-free
      uint4 h8 = hv4[khalf * 16 + k8];         // broadcast (2 addrs/wave: free)
      a0 = dot2(w8.x, h8.x, a0);
      a1 = dot2(w8.y, h8.y, a1);
      a2 = dot2(w8.z, h8.z, a2);
      a3 = dot2(w8.w, h8.w, a3);
    }
    float acc = (a0 + a1) + (a2 + a3);
    acc += __shfl_xor(acc, 32, 64);            // combine K-halves
    if (l < 32) gbuf[wv][c_loc] = acc + pv;
    __syncthreads();                           // B2: gates ready (hbits free)

    // --- gate nonlinearity + publish (wave 0, lanes 0..31)
    if (t < 32) {
      float gi = gbuf[0][t], gf = gbuf[1][t], gg = gbuf[2][t], go = gbuf[3][t];
      c = sigm(gf) * c + sigm(gi) * tanhf(gg);
      float hn = sigm(go) * tanhf(c);
      hstash[t] = hn;                          // wave-sync LDS, no barrier
      if (!enc) hs[((size_t)(step - Ss) * Bb + b) * Hh + j * 32 + t] = hn;
      if ((t & 1) == 0) {
        union { _Float16 f; unsigned short u; } u0, u1;
        u0.f = (_Float16)hn;
        u1.f = (_Float16)hstash[t + 1];
        u64 wd = ((u64)(unsigned)(step + 1) << 32) |
                 ((unsigned)u1.u << 16) | (unsigned)u0.u;
        __hip_atomic_store(
            hword + ((size_t)((step + 1) & 1) * 32 + b) * 128 + j * 16 + (t >> 1),
            wd, __ATOMIC_RELAXED, __HIP_MEMORY_SCOPE_AGENT);
      }
    }
    // no barrier here: next iteration's B1 orders gbuf reuse; hbits rewrite
    // happens post-B2 and its readers finished pre-B2.
  }
}

// --- out[:,0,:] = 0
__global__ __launch_bounds__(256) void k_zero0(float* __restrict__ out) {
  int v = blockIdx.x * 256 + threadIdx.x;       // grid.x = 125 -> exactly 32000
  out[(size_t)blockIdx.y * OUT_BT + v] = 0.0f;
}

// --- FC: logits[row=t*32+b][v] = hs[row] . fc_W[v] + fc_b[v] -> out[b][t+1][v]
// 64x64 tile per WG, bf16 MFMA 16x16x32, K=256 staged in two 128-halves.
__global__ __launch_bounds__(256) void k_fc(const float* __restrict__ hs,
                                            const float* __restrict__ fcW,
                                            const float* __restrict__ fcb,
                                            float* __restrict__ out) {
  constexpr int LDH = 136;                      // +8 halves pad: 2-way conflicts only
  __shared__ __align__(16) unsigned short As[64 * LDH];
  __shared__ __align__(16) unsigned short Bs[64 * LDH];
  int n0 = blockIdx.x * 64, m0 = blockIdx.y * 64;
  int tid = threadIdx.x;
  int lane = tid & 63, wave = tid >> 6;
  int l15 = lane & 15, q = lane >> 4;
  int msub = (wave & 1) * 32, nsub = (wave >> 1) * 32;
  f32x4 acc[2][2] = {};

  for (int kb = 0; kb < 2; ++kb) {
#pragma unroll
    for (int r = 0; r < 4; ++r) {
      int vecid = tid + 256 * r;                // 0..1023
      int i = vecid >> 4;                       // row 0..63
      int kk = (vecid & 15) * 8;                // 0..120
      int gk = kb * 128 + kk;
      short8 va, vb;
      int gm = m0 + i;
      if (gm < MR) {
        const float* p = hs + (size_t)gm * Hh + gk;
#pragma unroll
        for (int e = 0; e < 8; ++e) va[e] = (short)f2bf(p[e]);
      } else {
#pragma unroll
        for (int e = 0; e < 8; ++e) va[e] = 0;
      }
      const float* pb = fcW + (size_t)(n0 + i) * Hh + gk;
#pragma unroll
      for (int e = 0; e < 8; ++e) vb[e] = (short)f2bf(pb[e]);
      *(short8*)&As[i * LDH + kk] = va;
      *(short8*)&Bs[i * LDH + kk] = vb;
    }
    __syncthreads();
#pragma unroll
    for (int ks = 0; ks < 4; ++ks) {
      int koff = ks * 32 + q * 8;
      short8 a0 = *(const short8*)&As[(msub + l15) * LDH + koff];
      short8 a1 = *(const short8*)&As[(msub + 16 + l15) * LDH + koff];
      short8 b0 = *(const short8*)&Bs[(nsub + l15) * LDH + koff];
      short8 b1 = *(const short8*)&Bs[(nsub + 16 + l15) * LDH + koff];
      acc[0][0] = __builtin_amdgcn_mfma_f32_16x16x32_bf16(a0, b0, acc[0][0], 0, 0, 0);
      acc[0][1] = __builtin_amdgcn_mfma_f32_16x16x32_bf16(a0, b1, acc[0][1], 0, 0, 0);
      acc[1][0] = __builtin_amdgcn_mfma_f32_16x16x32_bf16(a1, b0, acc[1][0], 0, 0, 0);
      acc[1][1] = __builtin_amdgcn_mfma_f32_16x16x32_bf16(a1, b1, acc[1][1], 0, 0, 0);
    }
    __syncthreads();
  }
  // epilogue: D[row=q*4+r][col=l15] per 16x16 sub-tile (m89-verified layout)
#pragma unroll
  for (int ni = 0; ni < 2; ++ni) {
    int gn = n0 + nsub + ni * 16 + l15;
    float bv = fcb[gn];
#pragma unroll
    for (int mi = 0; mi < 2; ++mi) {
#pragma unroll
      for (int r = 0; r < 4; ++r) {
        int gm = m0 + msub + mi * 16 + q * 4 + r;
        if (gm < MR) {
          int tt = gm >> 5, bb = gm & 31;
          out[(size_t)bb * OUT_BT + (size_t)(tt + 1) * Vv + gn] = acc[mi][ni][r] + bv;
        }
      }
    }
  }
}

extern "C" void kernel_launch(void* const* d_in, const int* in_sizes, int n_in,
                              void* d_out, int out_size, void* d_ws, size_t ws_size,
                              hipStream_t stream) {
  const int*   src     = (const int*)d_in[0];
  const int*   trg     = (const int*)d_in[1];
  const float* enc_emb = (const float*)d_in[2];
  const float* enc_Wih = (const float*)d_in[3];
  const float* enc_Whh = (const float*)d_in[4];
  const float* enc_b   = (const float*)d_in[5];
  const float* dec_emb = (const float*)d_in[6];
  const float* dec_Wih = (const float*)d_in[7];
  const float* dec_Whh = (const float*)d_in[8];
  const float* dec_b   = (const float*)d_in[9];
  const float* fc_W    = (const float*)d_in[10];
  const float* fc_b    = (const float*)d_in[11];
  float* out = (float*)d_out;

  // scratch carved from d_out (fully dead before k_zero0/k_fc write output)
  char* ob = (char*)d_out;
  float*     enc_pre = (float*)(ob + OFF_ENCPRE);
  float*     dec_pre = (float*)(ob + OFF_DECPRE);
  _Float16*  WqE     = (_Float16*)(ob + OFF_WQE);
  _Float16*  WqD     = (_Float16*)(ob + OFF_WQD);
  float*     WpE     = (float*)(ob + OFF_WPE);
  float*     WpD     = (float*)(ob + OFF_WPD);
  u64*       hword   = (u64*)(ob + OFF_HW);
  float*     hs      = (float*)d_ws;   // 63*32*256 f32 = 8,257,536 B

  k_init<<<32, 256, 0, stream>>>(hword);
  k_pack_whh<<<1024, 256, 0, stream>>>(enc_Whh, WqE);
  k_pack_whh<<<1024, 256, 0, stream>>>(dec_Whh, WqD);
  k_pack_wih<<<512, 256, 0, stream>>>(enc_Wih, WpE);
  k_pack_wih<<<512, 256, 0, stream>>>(dec_Wih, WpD);
  k_pre<<<508, 1024, 0, stream>>>(src, trg, enc_emb, dec_emb, WpE, WpD,
                                  enc_b, dec_b, enc_pre, dec_pre);
  k_lstm2<<<256, 256, 0, stream>>>(enc_pre, dec_pre, WqE, WqD, hword, hs);
  k_zero0<<<dim3(125, 32), 256, 0, stream>>>(out);
  k_fc<<<dim3(500, 32), 256, 0, stream>>>(hs, fc_W, fc_b, out);
}

// Round 5
// 641.264 us; speedup vs baseline: 1.7004x; 1.1703x over previous
//
#include <hip/hip_runtime.h>

// ---------------------------------------------------------------------------
// Seq2Seq LSTM (enc 64 steps -> dec 63 steps -> FC to vocab), MI355X gfx950.
// Round 3: k_fc rebuilt as n-stripe GEMM (fetch-amplification fix).
//   k_pack_whh : Whh -> f16, packed-transposed [k8][row] (coalesced loads)
//   k_pack_wih : Wih -> f32, packed-transposed [e4][g]
//   k_pre      : embeddings + x@Wih^T + b for all 127 steps (parallel)
//   k_init     : zero the h-exchange word buffer (stale tags across replays!)
//   k_lstm2    : 256 WGs = 8 slices x 32 batch, weights LDS-resident, tagged
//                u64 h-exchange (unchanged from round 2); now emits decoder
//                hidden states directly as bf16 (same RNE rounding the old
//                k_fc applied -> bit-identical logits).
//   k_zero0    : out[:,0,:] = 0
//   k_fc       : grid=500 (one WG per 64-col fcW stripe). fcW stripe is read
//                and converted to bf16 ONCE per WG (was 32x), held in LDS for
//                an internal loop over all 32 m-tiles. hs (bf16, 1 MB) is
//                L2-resident and staged per m-tile with pure short8 copies.
//                Fetch: 521 MB -> ~35 MB ideal; kernel becomes write-bound.
// Scratch: pre-activations + packed weights + h-words carved from d_out (all
// dead before any output writes); d_ws holds bf16 decoder hiddens (1 MB).
// ---------------------------------------------------------------------------

typedef _Float16 f16x2 __attribute__((ext_vector_type(2)));
typedef short short8 __attribute__((ext_vector_type(8)));
typedef float f32x4 __attribute__((ext_vector_type(4)));
typedef unsigned long long u64;

#define DEV __device__ __forceinline__

static constexpr int Vv = 32000, Ee = 128, Hh = 256, Bb = 32, Ss = 64, Tt = 64;
static constexpr int G4 = 4 * Hh;             // 1024 gate outputs
static constexpr int MR = (Tt - 1) * Bb;      // 2016 logit rows
static constexpr size_t OUT_BT = (size_t)Tt * Vv;  // per-batch out stride (2,048,000)

// scratch carved from d_out (bytes)
static constexpr size_t OFF_ENCPRE = 0;                                    // 64*32*1024 f32
static constexpr size_t OFF_DECPRE = OFF_ENCPRE + (size_t)Ss * Bb * G4 * 4;  // 8,388,608
static constexpr size_t OFF_WQE    = OFF_DECPRE + (size_t)(Tt - 1) * Bb * G4 * 4; // +8,257,536
static constexpr size_t OFF_WQD    = OFF_WQE + (size_t)G4 * Hh * 2;        // +524,288
static constexpr size_t OFF_WPE    = OFF_WQD + (size_t)G4 * Hh * 2;
static constexpr size_t OFF_WPD    = OFF_WPE + (size_t)G4 * Ee * 4;
static constexpr size_t OFF_HW     = OFF_WPD + (size_t)G4 * Ee * 4;        // h-words: 2*32*128 u64 = 64 KB
// end = OFF_HW + 65,536 = 18,808,832 bytes << 262,144,000-byte output buffer

DEV float sigm(float x) { return 1.0f / (1.0f + expf(-x)); }

DEV unsigned short f2bf(float x) {
  unsigned u = __float_as_uint(x);
  u = u + 0x7fffu + ((u >> 16) & 1u);   // RNE
  return (unsigned short)(u >> 16);
}

DEV float dot2(unsigned wu, unsigned hu, float acc) {
  union { unsigned u; f16x2 v; } a, b;
  a.u = wu; b.u = hu;
#if __has_builtin(__builtin_amdgcn_fdot2)
  return __builtin_amdgcn_fdot2(a.v, b.v, acc, false);
#else
  return acc + (float)a.v.x * (float)b.v.x + (float)a.v.y * (float)b.v.y;
#endif
}

// --- pack Whh [1024][256] f32 -> f16 layout: dst[((k>>3)*1024 + r)*8 + (k&7)]
__global__ __launch_bounds__(256) void k_pack_whh(const float* __restrict__ src,
                                                  _Float16* __restrict__ dst) {
  int tid = blockIdx.x * 256 + threadIdx.x;
  if (tid >= G4 * Hh) return;
  int r = tid >> 8, k = tid & 255;
  dst[((size_t)(k >> 3) * G4 + r) * 8 + (k & 7)] = (_Float16)src[tid];
}

// --- pack Wih [1024][128] f32 -> f32 layout: dst[((e>>2)*1024 + g)*4 + (e&3)]
__global__ __launch_bounds__(256) void k_pack_wih(const float* __restrict__ src,
                                                  float* __restrict__ dst) {
  int tid = blockIdx.x * 256 + threadIdx.x;
  if (tid >= G4 * Ee) return;
  int g = tid >> 7, e = tid & 127;
  dst[((size_t)(e >> 2) * G4 + g) * 4 + (e & 3)] = src[tid];
}

// --- zero the h-exchange buffer (must run every launch: tags repeat across
// graph replays and a stale tag==step word would be consumed as fresh data)
__global__ __launch_bounds__(256) void k_init(u64* __restrict__ w) {
  w[blockIdx.x * 256 + threadIdx.x] = 0ull;   // grid 32 -> 8192 words
}

// --- pre[step][b][g] = emb[tok][.] @ Wih^T + b   (127 steps x 32 batch x 1024)
// grid: 127*4 blocks (4 batch-groups of 8), 1024 threads (one per gate col)
__global__ __launch_bounds__(1024) void k_pre(
    const int* __restrict__ src, const int* __restrict__ trg,
    const float* __restrict__ enc_emb, const float* __restrict__ dec_emb,
    const float* __restrict__ WpE, const float* __restrict__ WpD,
    const float* __restrict__ enc_b, const float* __restrict__ dec_b,
    float* __restrict__ enc_pre, float* __restrict__ dec_pre) {
  int blk = blockIdx.x;           // 0..507
  int step = blk >> 2;            // 0..126
  int b0 = (blk & 3) * 8;
  bool enc = step < Ss;
  int ts = enc ? step : step - Ss;            // enc s or dec t
  const int*   tok  = enc ? src : trg;
  const float* emb  = enc ? enc_emb : dec_emb;
  const float* Wp   = enc ? WpE : WpD;
  const float* bias = enc ? enc_b : dec_b;
  float* pre = enc ? (enc_pre + ((size_t)step * Bb + b0) * G4)
                   : (dec_pre + ((size_t)(step - Ss) * Bb + b0) * G4);

  __shared__ __align__(16) float xs[8][128];
  int tid = threadIdx.x;
  {
    int bl = tid >> 7, e = tid & 127;
    int token = tok[(b0 + bl) * 64 + ts];
    xs[bl][e] = emb[(size_t)token * Ee + e];
  }
  __syncthreads();

  int g = tid;
  float acc[8];
  float bv = bias[g];
#pragma unroll
  for (int bb = 0; bb < 8; ++bb) acc[bb] = bv;

  const f32x4* w4 = (const f32x4*)Wp;
  const f32x4(*x4)[32] = (const f32x4(*)[32])xs;
#pragma unroll 4
  for (int e4 = 0; e4 < 32; ++e4) {
    f32x4 w = w4[(size_t)e4 * G4 + g];
#pragma unroll
    for (int bb = 0; bb < 8; ++bb) {
      f32x4 xv = x4[bb][e4];
      acc[bb] += w.x * xv.x + w.y * xv.y + w.z * xv.z + w.w * xv.w;
    }
  }
#pragma unroll
  for (int bb = 0; bb < 8; ++bb) pre[(size_t)bb * G4 + g] = acc[bb];
}

// --- distributed sequential recurrence: 8 WGs per batch element.
// blockIdx = j*32 + b. Thread map (256 threads): wave wv = gate (i,f,g,o),
// lane&31 = local column, lane>>5 = K-half. Weight row = wv*256+j*32+(l&31).
__global__ __launch_bounds__(256, 1) void k_lstm2(
    const float* __restrict__ enc_pre, const float* __restrict__ dec_pre,
    const _Float16* __restrict__ WqE, const _Float16* __restrict__ WqD,
    u64* __restrict__ hword, unsigned short* __restrict__ hsb) {
  const int bid = blockIdx.x;
  const int j = bid >> 5, b = bid & 31;
  const int t = threadIdx.x;
  const int wv = t >> 6, l = t & 63;
  const int c_loc = l & 31, khalf = l >> 5;
  const int r_loc = wv * 32 + c_loc;           // 0..127 slice-local row
  const int row = wv * 256 + j * 32 + c_loc;   // global gate row

  __shared__ uint4 wlds[2][32][128];           // 128 KB: [enc/dec][K8][r_loc]
  __shared__ unsigned hbits[128];              // h: 128 x (2 f16)
  __shared__ float gbuf[4][32];
  __shared__ float hstash[32];

  // one-time stage: both weight slices -> LDS (64 KB each, read from L2 once)
  {
    const uint4* gE = (const uint4*)WqE + row;
    const uint4* gD = (const uint4*)WqD + row;
#pragma unroll 4
    for (int kk = 0; kk < 32; ++kk) wlds[0][kk][r_loc] = gE[(size_t)kk * G4];
#pragma unroll 4
    for (int kk = 0; kk < 32; ++kk) wlds[1][kk][r_loc] = gD[(size_t)kk * G4];
  }
  float c = 0.0f;                              // t<32: cell state, col j*32+t
  __syncthreads();

  for (int step = 0; step < 127; ++step) {
    const bool enc = step < Ss;
    const float* pre = (enc ? enc_pre + (size_t)step * (Bb * G4)
                            : dec_pre + (size_t)(step - Ss) * (Bb * G4)) +
                       (size_t)b * G4;
    float pv = pre[row];                       // issued early, used post-dots

    // --- acquire h_step (tag==step) into LDS; data rides in the tagged word
    if (t < 128) {
      if (step == 0) {
        hbits[t] = 0u;
      } else {
        u64* wp = hword + ((size_t)(step & 1) * 32 + b) * 128 + t;
        u64 v;
        do {
          v = __hip_atomic_load(wp, __ATOMIC_RELAXED, __HIP_MEMORY_SCOPE_AGENT);
        } while ((unsigned)(v >> 32) != (unsigned)step);
        hbits[t] = (unsigned)v;
      }
    }
    __syncthreads();                           // B1: h ready (also: gbuf free)

    // --- 128-element half-dot per thread, weights from LDS
    const uint4* wl = &wlds[enc ? 0 : 1][khalf * 16][0];
    const uint4* hv4 = (const uint4*)hbits;    // 32 x uint4 (8 f16 each)
    float a0 = 0.f, a1 = 0.f, a2 = 0.f, a3 = 0.f;
#pragma unroll
    for (int k8 = 0; k8 < 16; ++k8) {
      uint4 w8 = wl[k8 * 128 + r_loc];         // lanes contiguous: conflict-free
      uint4 h8 = hv4[khalf * 16 + k8];         // broadcast (2 addrs/wave: free)
      a0 = dot2(w8.x, h8.x, a0);
      a1 = dot2(w8.y, h8.y, a1);
      a2 = dot2(w8.z, h8.z, a2);
      a3 = dot2(w8.w, h8.w, a3);
    }
    float acc = (a0 + a1) + (a2 + a3);
    acc += __shfl_xor(acc, 32, 64);            // combine K-halves
    if (l < 32) gbuf[wv][c_loc] = acc + pv;
    __syncthreads();                           // B2: gates ready (hbits free)

    // --- gate nonlinearity + publish (wave 0, lanes 0..31)
    if (t < 32) {
      float gi = gbuf[0][t], gf = gbuf[1][t], gg = gbuf[2][t], go = gbuf[3][t];
      c = sigm(gf) * c + sigm(gi) * tanhf(gg);
      float hn = sigm(go) * tanhf(c);
      hstash[t] = hn;                          // wave-sync LDS, no barrier
      if (!enc)                                 // bf16 hidden for k_fc A-matrix
        hsb[((size_t)(step - Ss) * Bb + b) * Hh + j * 32 + t] = f2bf(hn);
      if ((t & 1) == 0) {
        union { _Float16 f; unsigned short u; } u0, u1;
        u0.f = (_Float16)hn;
        u1.f = (_Float16)hstash[t + 1];
        u64 wd = ((u64)(unsigned)(step + 1) << 32) |
                 ((unsigned)u1.u << 16) | (unsigned)u0.u;
        __hip_atomic_store(
            hword + ((size_t)((step + 1) & 1) * 32 + b) * 128 + j * 16 + (t >> 1),
            wd, __ATOMIC_RELAXED, __HIP_MEMORY_SCOPE_AGENT);
      }
    }
    // no barrier here: next iteration's B1 orders gbuf reuse; hbits rewrite
    // happens post-B2 and its readers finished pre-B2.
  }
}

// --- out[:,0,:] = 0
__global__ __launch_bounds__(256) void k_zero0(float* __restrict__ out) {
  int v = blockIdx.x * 256 + threadIdx.x;       // grid.x = 125 -> exactly 32000
  out[(size_t)blockIdx.y * OUT_BT + v] = 0.0f;
}

// --- FC: one WG per 64-col fcW stripe (grid 500). fcW stripe converted to
// bf16 once into LDS; loop over 32 m-tiles of 64 rows; hs is bf16 (1 MB,
// L2-resident across all WGs). 64x64 MFMA tile, K=256, bias-fused epilogue.
__global__ __launch_bounds__(256) void k_fc(const unsigned short* __restrict__ hsb,
                                            const float* __restrict__ fcW,
                                            const float* __restrict__ fcb,
                                            float* __restrict__ out) {
  constexpr int LDB = 264;                      // 256 + 8 halves pad (16 B)
  __shared__ __align__(16) unsigned short As[64 * LDB];
  __shared__ __align__(16) unsigned short Bs[64 * LDB];
  int n0 = blockIdx.x * 64;
  int tid = threadIdx.x;
  int lane = tid & 63, wave = tid >> 6;
  int l15 = lane & 15, q = lane >> 4;
  int msub = (wave & 1) * 32, nsub = (wave >> 1) * 32;

  // stage fcW stripe once: 64 rows x 256 k, f32 -> bf16
#pragma unroll
  for (int r = 0; r < 8; ++r) {
    int vecid = tid + 256 * r;                  // 0..2047
    int i = vecid >> 5;                         // row 0..63
    int kk = (vecid & 31) * 8;                  // 0..248
    const float* pb = fcW + (size_t)(n0 + i) * Hh + kk;
    short8 vb;
#pragma unroll
    for (int e = 0; e < 8; ++e) vb[e] = (short)f2bf(pb[e]);
    *(short8*)&Bs[i * LDB + kk] = vb;
  }
  float bv0 = fcb[n0 + nsub + l15];
  float bv1 = fcb[n0 + nsub + 16 + l15];

  for (int mt = 0; mt < 32; ++mt) {
    int m0 = mt * 64;
    __syncthreads();                            // prev MFMA reads done (As safe)
    // stage A m-tile: 64 rows x 256 halves, pure copy (already bf16)
#pragma unroll
    for (int r = 0; r < 8; ++r) {
      int vecid = tid + 256 * r;
      int i = vecid >> 5;
      int kk = (vecid & 31) * 8;
      int gm = m0 + i;
      short8 va = {};
      if (gm < MR) va = *(const short8*)&hsb[(size_t)gm * Hh + kk];
      *(short8*)&As[i * LDB + kk] = va;
    }
    __syncthreads();                            // As (and, iter 0, Bs) ready

    f32x4 acc[2][2] = {};
#pragma unroll
    for (int ks = 0; ks < 8; ++ks) {
      int koff = ks * 32 + q * 8;
      short8 a0 = *(const short8*)&As[(msub + l15) * LDB + koff];
      short8 a1 = *(const short8*)&As[(msub + 16 + l15) * LDB + koff];
      short8 b0 = *(const short8*)&Bs[(nsub + l15) * LDB + koff];
      short8 b1 = *(const short8*)&Bs[(nsub + 16 + l15) * LDB + koff];
      acc[0][0] = __builtin_amdgcn_mfma_f32_16x16x32_bf16(a0, b0, acc[0][0], 0, 0, 0);
      acc[0][1] = __builtin_amdgcn_mfma_f32_16x16x32_bf16(a0, b1, acc[0][1], 0, 0, 0);
      acc[1][0] = __builtin_amdgcn_mfma_f32_16x16x32_bf16(a1, b0, acc[1][0], 0, 0, 0);
      acc[1][1] = __builtin_amdgcn_mfma_f32_16x16x32_bf16(a1, b1, acc[1][1], 0, 0, 0);
    }
    // epilogue: D[row=q*4+r][col=l15] per 16x16 sub-tile (m89-verified layout)
#pragma unroll
    for (int ni = 0; ni < 2; ++ni) {
      int gn = n0 + nsub + ni * 16 + l15;
      float bv = ni ? bv1 : bv0;
#pragma unroll
      for (int mi = 0; mi < 2; ++mi) {
#pragma unroll
        for (int r = 0; r < 4; ++r) {
          int gm = m0 + msub + mi * 16 + q * 4 + r;
          if (gm < MR) {
            int tt = gm >> 5, bb = gm & 31;
            out[(size_t)bb * OUT_BT + (size_t)(tt + 1) * Vv + gn] = acc[mi][ni][r] + bv;
          }
        }
      }
    }
  }
}

extern "C" void kernel_launch(void* const* d_in, const int* in_sizes, int n_in,
                              void* d_out, int out_size, void* d_ws, size_t ws_size,
                              hipStream_t stream) {
  const int*   src     = (const int*)d_in[0];
  const int*   trg     = (const int*)d_in[1];
  const float* enc_emb = (const float*)d_in[2];
  const float* enc_Wih = (const float*)d_in[3];
  const float* enc_Whh = (const float*)d_in[4];
  const float* enc_b   = (const float*)d_in[5];
  const float* dec_emb = (const float*)d_in[6];
  const float* dec_Wih = (const float*)d_in[7];
  const float* dec_Whh = (const float*)d_in[8];
  const float* dec_b   = (const float*)d_in[9];
  const float* fc_W    = (const float*)d_in[10];
  const float* fc_b    = (const float*)d_in[11];
  float* out = (float*)d_out;

  // scratch carved from d_out (fully dead before k_zero0/k_fc write output)
  char* ob = (char*)d_out;
  float*     enc_pre = (float*)(ob + OFF_ENCPRE);
  float*     dec_pre = (float*)(ob + OFF_DECPRE);
  _Float16*  WqE     = (_Float16*)(ob + OFF_WQE);
  _Float16*  WqD     = (_Float16*)(ob + OFF_WQD);
  float*     WpE     = (float*)(ob + OFF_WPE);
  float*     WpD     = (float*)(ob + OFF_WPD);
  u64*       hword   = (u64*)(ob + OFF_HW);
  unsigned short* hsb = (unsigned short*)d_ws;   // 2016*256 bf16 = 1,032,192 B

  k_init<<<32, 256, 0, stream>>>(hword);
  k_pack_whh<<<1024, 256, 0, stream>>>(enc_Whh, WqE);
  k_pack_whh<<<1024, 256, 0, stream>>>(dec_Whh, WqD);
  k_pack_wih<<<512, 256, 0, stream>>>(enc_Wih, WpE);
  k_pack_wih<<<512, 256, 0, stream>>>(dec_Wih, WpD);
  k_pre<<<508, 1024, 0, stream>>>(src, trg, enc_emb, dec_emb, WpE, WpD,
                                  enc_b, dec_b, enc_pre, dec_pre);
  k_lstm2<<<256, 256, 0, stream>>>(enc_pre, dec_pre, WqE, WqD, hword, hsb);
  k_zero0<<<dim3(125, 32), 256, 0, stream>>>(out);
  k_fc<<<dim3(500), 256, 0, stream>>>(hsb, fc_W, fc_b, out);
}

// Round 10
// 637.257 us; speedup vs baseline: 1.7111x; 1.0063x over previous
//
#include <hip/hip_runtime.h>

// ---------------------------------------------------------------------------
// Seq2Seq LSTM (enc 64 steps -> dec 63 steps -> FC to vocab), MI355X gfx950.
// Round 6: sentinel-poll h-exchange + merged prep + folded zero0 (4 launches).
//   k_prep  : ONE kernel = zero h-words + pack WhhE/WhhD (f16, [k8][row]) +
//             pack WihE/WihD (f32, [e4][g]). All writes 16 B/thread coalesced
//             (old packs scattered 16 B chunks -> poor store efficiency).
//   k_pre   : embeddings + x@Wih^T + b for all 127 steps (parallel).
//   k_lstm3 : 256 WGs = 8 slices x 32 batch, weights LDS-resident (128 KB,
//             1 WG/CU). Tagged u64 h-exchange, parity double-buffered, but
//             polling is now SENTINEL-BASED: 16 lanes per peer spin on one
//             shared word (coalesces to ~1 LLC request/retry vs 112 spinning
//             words before), then one-shot confirm own tagged word. Own-slice
//             h goes straight to LDS at publish. Chain safety identical to
//             the proven R2 protocol (tag rides in every word; publish of
//             h_{s+2} only after receiving h_{s+1} from all peers => all
//             peers consumed h_s; exact-tag spin + zero-init => no aliasing).
//   k_fc    : grid=500 n-stripes; fcW stripe -> bf16 -> LDS once; loop over
//             32 m-tiles; bf16 MFMA 16x16x32; prologue zeroes out[:,0,stripe]
//             (replaces k_zero0 launch).
// Scratch: pre-activations + packed weights + h-words carved from d_out (all
// dead before any output writes); d_ws holds bf16 decoder hiddens (1 MB).
// ---------------------------------------------------------------------------

typedef _Float16 f16x2 __attribute__((ext_vector_type(2)));
typedef _Float16 f16x8 __attribute__((ext_vector_type(8)));
typedef short short8 __attribute__((ext_vector_type(8)));
typedef float f32x4 __attribute__((ext_vector_type(4)));
typedef unsigned long long u64;

#define DEV __device__ __forceinline__

static constexpr int Vv = 32000, Ee = 128, Hh = 256, Bb = 32, Ss = 64, Tt = 64;
static constexpr int G4 = 4 * Hh;             // 1024 gate outputs
static constexpr int MR = (Tt - 1) * Bb;      // 2016 logit rows
static constexpr size_t OUT_BT = (size_t)Tt * Vv;  // per-batch out stride (2,048,000)

// scratch carved from d_out (bytes)
static constexpr size_t OFF_ENCPRE = 0;                                    // 64*32*1024 f32
static constexpr size_t OFF_DECPRE = OFF_ENCPRE + (size_t)Ss * Bb * G4 * 4;  // 8,388,608
static constexpr size_t OFF_WQE    = OFF_DECPRE + (size_t)(Tt - 1) * Bb * G4 * 4; // +8,257,536
static constexpr size_t OFF_WQD    = OFF_WQE + (size_t)G4 * Hh * 2;        // +524,288
static constexpr size_t OFF_WPE    = OFF_WQD + (size_t)G4 * Hh * 2;
static constexpr size_t OFF_WPD    = OFF_WPE + (size_t)G4 * Ee * 4;
static constexpr size_t OFF_HW     = OFF_WPD + (size_t)G4 * Ee * 4;        // h-words: 2*32*128 u64 = 64 KB
// end = OFF_HW + 65,536 = 18,808,832 bytes << 262,144,000-byte output buffer

DEV float sigm(float x) { return 1.0f / (1.0f + expf(-x)); }

DEV unsigned short f2bf(float x) {
  unsigned u = __float_as_uint(x);
  u = u + 0x7fffu + ((u >> 16) & 1u);   // RNE
  return (unsigned short)(u >> 16);
}

DEV float dot2(unsigned wu, unsigned hu, float acc) {
  union { unsigned u; f16x2 v; } a, b;
  a.u = wu; b.u = hu;
#if __has_builtin(__builtin_amdgcn_fdot2)
  return __builtin_amdgcn_fdot2(a.v, b.v, acc, false);
#else
  return acc + (float)a.v.x * (float)b.v.x + (float)a.v.y * (float)b.v.y;
#endif
}

// --- merged prep: zero h-words + pack Whh (f16) + pack Wih (f32).
// grid 544 x 256:
//   blk [0,32)    : hword zero (graph replays repeat tags -> must re-zero)
//   blk [32,288)  : Whh pack, 128 blocks per matrix; thread u=(k8,r) reads
//                   Whh[r][k8*8..+8] and writes dst[u*8..+8] (16 B coalesced)
//   blk [288,544) : Wih pack, thread u=(e4,g) reads Wih[g][e4*4..+4] and
//                   writes dst[u*4..+4] (16 B coalesced)
__global__ __launch_bounds__(256) void k_prep(
    const float* __restrict__ WhhE_s, const float* __restrict__ WhhD_s,
    const float* __restrict__ WihE_s, const float* __restrict__ WihD_s,
    _Float16* __restrict__ WqE, _Float16* __restrict__ WqD,
    float* __restrict__ WpE, float* __restrict__ WpD,
    u64* __restrict__ hword) {
  int blk = blockIdx.x, t = threadIdx.x;
  if (blk < 32) { hword[blk * 256 + t] = 0ull; return; }
  blk -= 32;
  if (blk < 256) {
    const float* src = (blk < 128) ? WhhE_s : WhhD_s;
    _Float16*    dst = (blk < 128) ? WqE : WqD;
    int u = (blk & 127) * 256 + t;              // 0..32767
    int k8 = u >> 10, r = u & 1023;
    const float* sp = src + r * Hh + k8 * 8;
    f16x8 v;
#pragma unroll
    for (int e = 0; e < 8; ++e) v[e] = (_Float16)sp[e];
    *(f16x8*)&dst[(size_t)u * 8] = v;
    return;
  }
  blk -= 256;
  {
    const float* src = (blk < 128) ? WihE_s : WihD_s;
    float*       dst = (blk < 128) ? WpE : WpD;
    int u = (blk & 127) * 256 + t;              // 0..32767
    int e4 = u >> 10, g = u & 1023;
    f32x4 v = *(const f32x4*)(src + g * Ee + e4 * 4);
    *(f32x4*)&dst[(size_t)u * 4] = v;
  }
}

// --- pre[step][b][g] = emb[tok][.] @ Wih^T + b   (127 steps x 32 batch x 1024)
// grid: 127*4 blocks (4 batch-groups of 8), 1024 threads (one per gate col)
__global__ __launch_bounds__(1024) void k_pre(
    const int* __restrict__ src, const int* __restrict__ trg,
    const float* __restrict__ enc_emb, const float* __restrict__ dec_emb,
    const float* __restrict__ WpE, const float* __restrict__ WpD,
    const float* __restrict__ enc_b, const float* __restrict__ dec_b,
    float* __restrict__ enc_pre, float* __restrict__ dec_pre) {
  int blk = blockIdx.x;           // 0..507
  int step = blk >> 2;            // 0..126
  int b0 = (blk & 3) * 8;
  bool enc = step < Ss;
  int ts = enc ? step : step - Ss;            // enc s or dec t
  const int*   tok  = enc ? src : trg;
  const float* emb  = enc ? enc_emb : dec_emb;
  const float* Wp   = enc ? WpE : WpD;
  const float* bias = enc ? enc_b : dec_b;
  float* pre = enc ? (enc_pre + ((size_t)step * Bb + b0) * G4)
                   : (dec_pre + ((size_t)(step - Ss) * Bb + b0) * G4);

  __shared__ __align__(16) float xs[8][128];
  int tid = threadIdx.x;
  {
    int bl = tid >> 7, e = tid & 127;
    int token = tok[(b0 + bl) * 64 + ts];
    xs[bl][e] = emb[(size_t)token * Ee + e];
  }
  __syncthreads();

  int g = tid;
  float acc[8];
  float bv = bias[g];
#pragma unroll
  for (int bb = 0; bb < 8; ++bb) acc[bb] = bv;

  const f32x4* w4 = (const f32x4*)Wp;
  const f32x4(*x4)[32] = (const f32x4(*)[32])xs;
#pragma unroll 4
  for (int e4 = 0; e4 < 32; ++e4) {
    f32x4 w = w4[(size_t)e4 * G4 + g];
#pragma unroll
    for (int bb = 0; bb < 8; ++bb) {
      f32x4 xv = x4[bb][e4];
      acc[bb] += w.x * xv.x + w.y * xv.y + w.z * xv.z + w.w * xv.w;
    }
  }
#pragma unroll
  for (int bb = 0; bb < 8; ++bb) pre[(size_t)bb * G4 + g] = acc[bb];
}

// --- distributed sequential recurrence: 8 WGs per batch element.
// blockIdx = j*32 + b. Thread map (256 threads): wave wv = gate (i,f,g,o),
// lane&31 = local column, lane>>5 = K-half. Weight row = wv*256+j*32+(l&31).
// h-exchange: sentinel poll (word p*16+15 per peer, 16 lanes coalesce on it)
// then tagged confirm of own word; own slice written to LDS at publish.
__global__ __launch_bounds__(256, 1) void k_lstm3(
    const float* __restrict__ enc_pre, const float* __restrict__ dec_pre,
    const _Float16* __restrict__ WqE, const _Float16* __restrict__ WqD,
    u64* __restrict__ hword, unsigned short* __restrict__ hsb) {
  const int bid = blockIdx.x;
  const int j = bid >> 5, b = bid & 31;
  const int t = threadIdx.x;
  const int wv = t >> 6, l = t & 63;
  const int c_loc = l & 31, khalf = l >> 5;
  const int r_loc = wv * 32 + c_loc;           // 0..127 slice-local row
  const int row = wv * 256 + j * 32 + c_loc;   // global gate row

  __shared__ uint4 wlds[2][32][128];           // 128 KB: [enc/dec][K8][r_loc]
  __shared__ unsigned hbits[128];              // h: 128 x (2 f16)
  __shared__ float gbuf[4][32];
  __shared__ float hstash[32];

  // one-time stage: both weight slices -> LDS (64 KB each, read from L2 once)
  {
    const uint4* gE = (const uint4*)WqE + row;
    const uint4* gD = (const uint4*)WqD + row;
#pragma unroll 4
    for (int kk = 0; kk < 32; ++kk) wlds[0][kk][r_loc] = gE[(size_t)kk * G4];
#pragma unroll 4
    for (int kk = 0; kk < 32; ++kk) wlds[1][kk][r_loc] = gD[(size_t)kk * G4];
  }
  float c = 0.0f;                              // t<32: cell state, col j*32+t
  __syncthreads();

  for (int step = 0; step < 127; ++step) {
    const bool enc = step < Ss;
    const float* pre = (enc ? enc_pre + (size_t)step * (Bb * G4)
                            : dec_pre + (size_t)(step - Ss) * (Bb * G4)) +
                       (size_t)b * G4;
    float pv = pre[row];                       // issued early, used post-dots

    // --- acquire h_step into LDS (sentinel poll; data rides in tagged words)
    if (t < 128) {
      if (step == 0) {
        hbits[t] = 0u;
      } else {
        const int p = t >> 4;                  // peer slice for this word
        if (p != j) {                          // own slice filled at publish
          u64* base = hword + ((size_t)(step & 1) * 32 + b) * 128;
          u64* sp = base + p * 16 + 15;        // sentinel: 16 lanes coalesce
          u64 s;
          do {
            s = __hip_atomic_load(sp, __ATOMIC_RELAXED, __HIP_MEMORY_SCOPE_AGENT);
          } while ((unsigned)(s >> 32) != (unsigned)step);
          u64 v;
          if ((t & 15) == 15) {
            v = s;                             // sentinel IS this lane's word
          } else {
            u64* wp = base + t;
            do {                               // usually 1-shot after sentinel
              v = __hip_atomic_load(wp, __ATOMIC_RELAXED, __HIP_MEMORY_SCOPE_AGENT);
            } while ((unsigned)(v >> 32) != (unsigned)step);
          }
          hbits[t] = (unsigned)v;
        }
      }
    }
    __syncthreads();                           // B1: h ready (also: gbuf free)

    // --- 128-element half-dot per thread, weights from LDS
    const uint4* wl = &wlds[enc ? 0 : 1][khalf * 16][0];
    const uint4* hv4 = (const uint4*)hbits;    // 32 x uint4 (8 f16 each)
    float a0 = 0.f, a1 = 0.f, a2 = 0.f, a3 = 0.f;
#pragma unroll
    for (int k8 = 0; k8 < 16; ++k8) {
      uint4 w8 = wl[k8 * 128 + r_loc];         // lanes contiguous: conflict-free
      uint4 h8 = hv4[khalf * 16 + k8];         // broadcast (2 addrs/wave: free)
      a0 = dot2(w8.x, h8.x, a0);
      a1 = dot2(w8.y, h8.y, a1);
      a2 = dot2(w8.z, h8.z, a2);
      a3 = dot2(w8.w, h8.w, a3);
    }
    float acc = (a0 + a1) + (a2 + a3);
    acc += __shfl_xor(acc, 32, 64);            // combine K-halves
    if (l < 32) gbuf[wv][c_loc] = acc + pv;
    __syncthreads();                           // B2: gates ready (hbits free)

    // --- gate nonlinearity + publish (wave 0, lanes 0..31)
    if (t < 32) {
      float gi = gbuf[0][t], gf = gbuf[1][t], gg = gbuf[2][t], go = gbuf[3][t];
      c = sigm(gf) * c + sigm(gi) * tanhf(gg);
      float hn = sigm(go) * tanhf(c);
      hstash[t] = hn;                          // wave-sync LDS, no barrier
      if (!enc)                                 // bf16 hidden for k_fc A-matrix
        hsb[((size_t)(step - Ss) * Bb + b) * Hh + j * 32 + t] = f2bf(hn);
      if ((t & 1) == 0) {
        union { _Float16 f; unsigned short u; } u0, u1;
        u0.f = (_Float16)hn;
        u1.f = (_Float16)hstash[t + 1];
        u64 wd = ((u64)(unsigned)(step + 1) << 32) |
                 ((unsigned)u1.u << 16) | (unsigned)u0.u;
        __hip_atomic_store(
            hword + ((size_t)((step + 1) & 1) * 32 + b) * 128 + j * 16 + (t >> 1),
            wd, __ATOMIC_RELAXED, __HIP_MEMORY_SCOPE_AGENT);
        hbits[j * 16 + (t >> 1)] = (unsigned)wd;  // own slice for next step
      }
    }
    // no barrier here: next iteration's B1 orders gbuf/hbits reuse.
  }
}

// --- FC: one WG per 64-col fcW stripe (grid 500). Prologue zeroes
// out[:,0,stripe] (replaces k_zero0). fcW stripe converted to bf16 once into
// LDS; loop over 32 m-tiles of 64 rows; hs is bf16 (1 MB, L2-resident).
// 64x64 MFMA tile, K=256, bias-fused epilogue.
__global__ __launch_bounds__(256) void k_fc(const unsigned short* __restrict__ hsb,
                                            const float* __restrict__ fcW,
                                            const float* __restrict__ fcb,
                                            float* __restrict__ out) {
  constexpr int LDB = 264;                      // 256 + 8 halves pad (16 B)
  __shared__ __align__(16) unsigned short As[64 * LDB];
  __shared__ __align__(16) unsigned short Bs[64 * LDB];
  int n0 = blockIdx.x * 64;
  int tid = threadIdx.x;
  int lane = tid & 63, wave = tid >> 6;
  int l15 = lane & 15, q = lane >> 4;
  int msub = (wave & 1) * 32, nsub = (wave >> 1) * 32;

  // zero out[:,0,n0:n0+64]  (2048 floats, 8 per thread, coalesced)
  {
    int idx = tid * 8;
    int zb = idx >> 6, off = idx & 63;
    float* zp = out + (size_t)zb * OUT_BT + n0 + off;
    f32x4 z = {};
    *(f32x4*)zp = z;
    *(f32x4*)(zp + 4) = z;
  }

  // stage fcW stripe once: 64 rows x 256 k, f32 -> bf16
#pragma unroll
  for (int r = 0; r < 8; ++r) {
    int vecid = tid + 256 * r;                  // 0..2047
    int i = vecid >> 5;                         // row 0..63
    int kk = (vecid & 31) * 8;                  // 0..248
    const float* pb = fcW + (size_t)(n0 + i) * Hh + kk;
    short8 vb;
#pragma unroll
    for (int e = 0; e < 8; ++e) vb[e] = (short)f2bf(pb[e]);
    *(short8*)&Bs[i * LDB + kk] = vb;
  }
  float bv0 = fcb[n0 + nsub + l15];
  float bv1 = fcb[n0 + nsub + 16 + l15];

  for (int mt = 0; mt < 32; ++mt) {
    int m0 = mt * 64;
    __syncthreads();                            // prev MFMA reads done (As safe)
    // stage A m-tile: 64 rows x 256 halves, pure copy (already bf16)
#pragma unroll
    for (int r = 0; r < 8; ++r) {
      int vecid = tid + 256 * r;
      int i = vecid >> 5;
      int kk = (vecid & 31) * 8;
      int gm = m0 + i;
      short8 va = {};
      if (gm < MR) va = *(const short8*)&hsb[(size_t)gm * Hh + kk];
      *(short8*)&As[i * LDB + kk] = va;
    }
    __syncthreads();                            // As (and, iter 0, Bs) ready

    f32x4 acc[2][2] = {};
#pragma unroll
    for (int ks = 0; ks < 8; ++ks) {
      int koff = ks * 32 + q * 8;
      short8 a0 = *(const short8*)&As[(msub + l15) * LDB + koff];
      short8 a1 = *(const short8*)&As[(msub + 16 + l15) * LDB + koff];
      short8 b0 = *(const short8*)&Bs[(nsub + l15) * LDB + koff];
      short8 b1 = *(const short8*)&Bs[(nsub + 16 + l15) * LDB + koff];
      acc[0][0] = __builtin_amdgcn_mfma_f32_16x16x32_bf16(a0, b0, acc[0][0], 0, 0, 0);
      acc[0][1] = __builtin_amdgcn_mfma_f32_16x16x32_bf16(a0, b1, acc[0][1], 0, 0, 0);
      acc[1][0] = __builtin_amdgcn_mfma_f32_16x16x32_bf16(a1, b0, acc[1][0], 0, 0, 0);
      acc[1][1] = __builtin_amdgcn_mfma_f32_16x16x32_bf16(a1, b1, acc[1][1], 0, 0, 0);
    }
    // epilogue: D[row=q*4+r][col=l15] per 16x16 sub-tile (m89-verified layout)
#pragma unroll
    for (int ni = 0; ni < 2; ++ni) {
      int gn = n0 + nsub + ni * 16 + l15;
      float bv = ni ? bv1 : bv0;
#pragma unroll
      for (int mi = 0; mi < 2; ++mi) {
#pragma unroll
        for (int r = 0; r < 4; ++r) {
          int gm = m0 + msub + mi * 16 + q * 4 + r;
          if (gm < MR) {
            int tt = gm >> 5, bb = gm & 31;
            out[(size_t)bb * OUT_BT + (size_t)(tt + 1) * Vv + gn] = acc[mi][ni][r] + bv;
          }
        }
      }
    }
  }
}

extern "C" void kernel_launch(void* const* d_in, const int* in_sizes, int n_in,
                              void* d_out, int out_size, void* d_ws, size_t ws_size,
                              hipStream_t stream) {
  const int*   src     = (const int*)d_in[0];
  const int*   trg     = (const int*)d_in[1];
  const float* enc_emb = (const float*)d_in[2];
  const float* enc_Wih = (const float*)d_in[3];
  const float* enc_Whh = (const float*)d_in[4];
  const float* enc_b   = (const float*)d_in[5];
  const float* dec_emb = (const float*)d_in[6];
  const float* dec_Wih = (const float*)d_in[7];
  const float* dec_Whh = (const float*)d_in[8];
  const float* dec_b   = (const float*)d_in[9];
  const float* fc_W    = (const float*)d_in[10];
  const float* fc_b    = (const float*)d_in[11];
  float* out = (float*)d_out;

  // scratch carved from d_out (fully dead before k_fc writes output)
  char* ob = (char*)d_out;
  float*     enc_pre = (float*)(ob + OFF_ENCPRE);
  float*     dec_pre = (float*)(ob + OFF_DECPRE);
  _Float16*  WqE     = (_Float16*)(ob + OFF_WQE);
  _Float16*  WqD     = (_Float16*)(ob + OFF_WQD);
  float*     WpE     = (float*)(ob + OFF_WPE);
  float*     WpD     = (float*)(ob + OFF_WPD);
  u64*       hword   = (u64*)(ob + OFF_HW);
  unsigned short* hsb = (unsigned short*)d_ws;   // 2016*256 bf16 = 1,032,192 B

  k_prep<<<544, 256, 0, stream>>>(enc_Whh, dec_Whh, enc_Wih, dec_Wih,
                                  WqE, WqD, WpE, WpD, hword);
  k_pre<<<508, 1024, 0, stream>>>(src, trg, enc_emb, dec_emb, WpE, WpD,
                                  enc_b, dec_b, enc_pre, dec_pre);
  k_lstm3<<<256, 256, 0, stream>>>(enc_pre, dec_pre, WqE, WqD, hword, hsb);
  k_fc<<<dim3(500), 256, 0, stream>>>(hsb, fc_W, fc_b, out);
}